// Round 1
// baseline (113.285 us; speedup 1.0000x reference)
//
#include <hip/hip_runtime.h>
#include <hip/hip_cooperative_groups.h>

namespace cg = cooperative_groups;

#define L_TOTAL 32768
#define D_MODEL 1024
#define NBLK    256                  // one block per CU, cooperative co-resident
#define NTHR    1024                 // 16 waves/block
#define CL      4096                 // l's staged in LDS per chunk (32 KB float2)
#define NCHUNK  (L_TOTAL / CL)       // 8
#define JITER   (CL / 256)           // 16 l's per thread per chunk

// One fused cooperative kernel. Block b owns d = 4b..4b+3 entirely:
//   phase 1: 4 d x 256 l-lanes; each thread sums sin over its 128 l's (staged via LDS)
//            -> shuffle+LDS reduce -> plain store signal into out[4b+di]. No atomics.
//   grid sync; every block copies full signal out[] -> LDS; grid sync (all reads done)
//   phase 3: matvec rows 4b..4b+3 from W (coalesced, each row read once), write out.
__global__ __launch_bounds__(NTHR, 4) void fused_kernel(const float* __restrict__ x,
                                                        const float* __restrict__ W,
                                                        const float* __restrict__ b,
                                                        float* __restrict__ out) {
    __shared__ float2 sxp[CL];          // {x[l], x[l]*log1p(l)}  32 KB
    __shared__ float  ssig[D_MODEL];    // full signal broadcast   4 KB
    __shared__ float  wsum[64];         // cross-wave reduce: [wave][di]
    __shared__ float  rsum[16];         // matvec partials: [r4][wave_in_row]

    const int tid  = threadIdx.x;
    const int blk  = blockIdx.x;
    const int lane = tid & 63;
    const int wv   = tid >> 6;          // wave 0..15
    const int di   = tid & 3;           // which of block's 4 d's
    const int li   = tid >> 2;          // l-lane 0..255
    const float t  = (float)(blk * 4 + di) * (1.0f / 1023.0f);  // linspace(0,1,1024)

    // ---- phase 1: signal[4b+di] = sum_l sin(2*pi*x[l]*(t + log1p(l))) ----
    float a = 0.f;
    for (int c = 0; c < NCHUNK; ++c) {
        const int cbase = c * CL;
        __syncthreads();                               // protect sxp reuse
        #pragma unroll
        for (int s = 0; s < CL / NTHR; ++s) {          // 4 coalesced stage loads
            const int idx = tid + s * NTHR;
            const int l   = cbase + idx;
            const float xv = x[l];
            sxp[idx] = make_float2(xv, xv * __logf(1.0f + (float)l));
        }
        __syncthreads();
        #pragma unroll
        for (int j = 0; j < JITER; ++j) {
            const float2 v = sxp[li + 256 * j];        // 16 addrs/wave, conflict-free
            const float g = __builtin_amdgcn_fractf(fmaf(v.x, t, v.y));
            a += __builtin_amdgcn_sinf(g);             // v_sin_f32: revolutions
        }
    }
    // reduce over li within wave: xor lane bits 2..5 (di in bits 0..1 untouched)
    a += __shfl_xor(a, 4, 64);
    a += __shfl_xor(a, 8, 64);
    a += __shfl_xor(a, 16, 64);
    a += __shfl_xor(a, 32, 64);
    if (lane < 4) wsum[wv * 4 + lane] = a;             // [wave][di]
    __syncthreads();
    if (tid < 64) {                                    // 16 waves x 4 di = 64 values
        float v = wsum[tid];                           // di = tid&3, w = tid>>2
        v += __shfl_xor(v, 4, 64);
        v += __shfl_xor(v, 8, 64);
        v += __shfl_xor(v, 16, 64);
        v += __shfl_xor(v, 32, 64);
        if (tid < 4) out[blk * 4 + tid] = v;           // plain store, no atomic
    }

    cg::this_grid().sync();            // all signal values landed in out[]

    ssig[tid] = out[tid];              // every block grabs the full signal (4 KB)

    cg::this_grid().sync();            // all blocks done READING out -> safe to overwrite

    // ---- phase 3: out[r] = b[r] + dot(signal, W[r,:]) for r = 4b..4b+3 ----
    const int r4  = tid >> 8;          // 0..3 (4 waves per row)
    const int cc  = tid & 255;         // float4 index within row
    const int row = blk * 4 + r4;
    const float4 w4 = ((const float4*)(W + (size_t)row * D_MODEL))[cc];  // coalesced
    const float4 s4 = ((const float4*)ssig)[cc];
    float sum = w4.x * s4.x + w4.y * s4.y + w4.z * s4.z + w4.w * s4.w;
    #pragma unroll
    for (int off = 32; off > 0; off >>= 1)
        sum += __shfl_down(sum, off, 64);
    if (lane == 0) rsum[wv] = sum;     // wv = r4*4 + wave_in_row
    __syncthreads();
    if (tid < 4) {
        const int r = blk * 4 + tid;
        out[r] = rsum[tid * 4] + rsum[tid * 4 + 1] + rsum[tid * 4 + 2]
               + rsum[tid * 4 + 3] + b[r];
    }
}

extern "C" void kernel_launch(void* const* d_in, const int* in_sizes, int n_in,
                              void* d_out, int out_size, void* d_ws, size_t ws_size,
                              hipStream_t stream) {
    const float* x = (const float*)d_in[0];   // inputs [32768]
    const float* W = (const float*)d_in[1];   // W [1024,1024]
    const float* b = (const float*)d_in[2];   // b [1024]
    float* out     = (float*)d_out;           // [1024]
    // No workspace, no memset, single cooperative launch.
    void* args[] = { (void*)&x, (void*)&W, (void*)&b, (void*)&out };
    hipLaunchCooperativeKernel((const void*)fused_kernel, dim3(NBLK), dim3(NTHR),
                               args, 0, stream);
}

// Round 2
// 90.020 us; speedup vs baseline: 1.2584x; 1.2584x over previous
//
#include <hip/hip_runtime.h>

#define L_TOTAL 32768
#define D_MODEL 1024
#define NBLK    256                  // one block per CU; all co-resident (cap >= 2x grid)
#define NTHR    1024                 // 16 waves/block
#define CL      4096                 // l's staged in LDS per chunk (32 KB float2)
#define NCHUNK  (L_TOTAL / CL)       // 8
#define JITER   (CL / 256)           // 16 l's per thread per chunk

// Monotonic ticket barrier counter; zero-initialized at module load, never reset
// (512 increments/iteration; wrap handled by signed-distance compare).
__device__ unsigned int g_bar = 0u;

__device__ __forceinline__ void grid_sync() {
    __syncthreads();   // compiler drains vmcnt/lgkmcnt before s_barrier: block's prior
                       // global ops (incl. agent-scope stores) have completed here.
    if (threadIdx.x == 0) {
        const unsigned int ticket =
            __hip_atomic_fetch_add(&g_bar, 1u, __ATOMIC_ACQ_REL, __HIP_MEMORY_SCOPE_AGENT);
        const unsigned int target = (ticket & ~(unsigned int)(NBLK - 1)) + NBLK;
        unsigned int cur;
        do {
            __builtin_amdgcn_s_sleep(2);
            cur = __hip_atomic_load(&g_bar, __ATOMIC_ACQUIRE, __HIP_MEMORY_SCOPE_AGENT);
        } while ((int)(cur - target) < 0);
    }
    __syncthreads();
}

// Single regular-launch kernel, same dataflow as the cooperative version:
//   phase 1: block b owns d = 4b..4b+3; sums sin over all l (x staged via LDS,
//            next chunk prefetched to registers) -> agent-scope store into out[4b+di].
//   grid_sync; every block pulls the full signal out[] -> LDS (agent loads);
//   grid_sync; phase 3: matvec rows 4b..4b+3 (W coalesced, read once), write out.
__global__ __launch_bounds__(NTHR) void fused_kernel(const float* __restrict__ x,
                                                     const float* __restrict__ W,
                                                     const float* __restrict__ b,
                                                     float* __restrict__ out) {
    __shared__ float2 sxp[CL];          // {x[l], x[l]*log1p(l)}  32 KB
    __shared__ float  ssig[D_MODEL];    // full signal broadcast   4 KB
    __shared__ float  wsum[64];         // cross-wave reduce: [wave][di]
    __shared__ float  rsum[16];         // matvec partials: [r4][wave_in_row]

    const int tid  = threadIdx.x;
    const int blk  = blockIdx.x;
    const int lane = tid & 63;
    const int wv   = tid >> 6;          // wave 0..15
    const int di   = tid & 3;           // which of block's 4 d's
    const int li   = tid >> 2;          // l-lane 0..255
    const float t  = (float)(blk * 4 + di) * (1.0f / 1023.0f);  // linspace(0,1,1024)

    // ---- phase 1: signal[4b+di] = sum_l sin(2*pi*x[l]*(t + log1p(l))) ----
    float xr[CL / NTHR];                // register prefetch of next chunk's x
    #pragma unroll
    for (int s = 0; s < CL / NTHR; ++s) xr[s] = x[tid + s * NTHR];

    float a = 0.f;
    for (int c = 0; c < NCHUNK; ++c) {
        const int cbase = c * CL;
        __syncthreads();                               // sxp free (prev chunk consumed)
        #pragma unroll
        for (int s = 0; s < CL / NTHR; ++s) {          // regs -> LDS (+ logf here)
            const int idx = tid + s * NTHR;
            const int l   = cbase + idx;
            sxp[idx] = make_float2(xr[s], xr[s] * __logf(1.0f + (float)l));
        }
        __syncthreads();
        if (c + 1 < NCHUNK) {                          // issue next chunk's loads now;
            const int nbase = (c + 1) * CL;            // latency hides under sin loop
            #pragma unroll
            for (int s = 0; s < CL / NTHR; ++s) xr[s] = x[nbase + tid + s * NTHR];
        }
        #pragma unroll
        for (int j = 0; j < JITER; ++j) {
            const float2 v = sxp[li + 256 * j];        // 16 addrs/wave, conflict-free
            const float g = __builtin_amdgcn_fractf(fmaf(v.x, t, v.y));
            a += __builtin_amdgcn_sinf(g);             // v_sin_f32: revolutions
        }
    }
    // reduce over li within wave: xor lane bits 2..5 (di in bits 0..1 untouched)
    a += __shfl_xor(a, 4, 64);
    a += __shfl_xor(a, 8, 64);
    a += __shfl_xor(a, 16, 64);
    a += __shfl_xor(a, 32, 64);
    if (lane < 4) wsum[wv * 4 + lane] = a;             // [wave][di]
    __syncthreads();
    if (tid < 64) {                                    // 16 waves x 4 di = 64 values
        float v = wsum[tid];                           // di = tid&3, w = tid>>2
        v += __shfl_xor(v, 4, 64);
        v += __shfl_xor(v, 8, 64);
        v += __shfl_xor(v, 16, 64);
        v += __shfl_xor(v, 32, 64);
        if (tid < 4)                                   // agent scope: visible cross-XCD
            __hip_atomic_store(&out[blk * 4 + tid], v,
                               __ATOMIC_RELEASE, __HIP_MEMORY_SCOPE_AGENT);
    }

    grid_sync();                       // all signal values landed in out[]

    ssig[tid] = __hip_atomic_load(&out[tid],           // bypass stale L1/L2
                                  __ATOMIC_RELAXED, __HIP_MEMORY_SCOPE_AGENT);

    grid_sync();                       // all blocks done READING out -> safe to overwrite

    // ---- phase 3: out[r] = b[r] + dot(signal, W[r,:]) for r = 4b..4b+3 ----
    const int r4  = tid >> 8;          // 0..3 (4 waves per row)
    const int cc  = tid & 255;         // float4 index within row
    const int row = blk * 4 + r4;
    const float4 w4 = ((const float4*)(W + (size_t)row * D_MODEL))[cc];  // coalesced
    const float4 s4 = ((const float4*)ssig)[cc];
    float sum = w4.x * s4.x + w4.y * s4.y + w4.z * s4.z + w4.w * s4.w;
    #pragma unroll
    for (int off = 32; off > 0; off >>= 1)
        sum += __shfl_down(sum, off, 64);
    if (lane == 0) rsum[wv] = sum;     // wv = r4*4 + wave_in_row
    __syncthreads();
    if (tid < 4) {
        const int r = blk * 4 + tid;
        out[r] = rsum[tid * 4] + rsum[tid * 4 + 1] + rsum[tid * 4 + 2]
               + rsum[tid * 4 + 3] + b[r];
    }
}

extern "C" void kernel_launch(void* const* d_in, const int* in_sizes, int n_in,
                              void* d_out, int out_size, void* d_ws, size_t ws_size,
                              hipStream_t stream) {
    const float* x = (const float*)d_in[0];   // inputs [32768]
    const float* W = (const float*)d_in[1];   // W [1024,1024]
    const float* b = (const float*)d_in[2];   // b [1024]
    float* out     = (float*)d_out;           // [1024]
    // Regular (graph-capturable) launch; no workspace, no memset, no cooperative API.
    fused_kernel<<<NBLK, NTHR, 0, stream>>>(x, W, b, out);
}

// Round 3
// 76.573 us; speedup vs baseline: 1.4794x; 1.1756x over previous
//
#include <hip/hip_runtime.h>

#define L_TOTAL 32768
#define D_MODEL 1024
#define LCHUNK  64                         // l's per signal block
#define NQ      (D_MODEL / 256)            // 4 d-quarters (256 threads each)
#define NBLK_S  ((L_TOTAL / LCHUNK) * NQ)  // 512 l-chunks x 4 quarters = 2048 blocks

// Stage 1: signal[d] = sum_l sin(2*pi * x[l] * (t[d] + log1p(l)))
// 2048 blocks x 256 thr (8 blocks/CU -> 32 waves/CU, full occupancy).
// Block (q, c): d = q*256 + tid, l in [c*64, c*64+64).
// Inner loop: wave-uniform LDS broadcast (1 address/iter), 4 accumulators,
// 64 iterations/thread. Phase in revolutions: v_sin_f32(fract(x*t + x*p)).
__global__ __launch_bounds__(256) void signal_kernel(const float* __restrict__ x,
                                                     float* __restrict__ signal) {
    __shared__ float2 sxp[LCHUNK];          // {x[l], x[l]*log1p(l)}  512 B
    const int tid   = threadIdx.x;
    const int q     = blockIdx.x & (NQ - 1);
    const int c     = blockIdx.x >> 2;
    const int lbase = c * LCHUNK;

    if (tid < LCHUNK) {
        const int l   = lbase + tid;
        const float xv = x[l];
        sxp[tid] = make_float2(xv, xv * __logf(1.0f + (float)l));
    }
    __syncthreads();

    const int   d = q * 256 + tid;
    const float t = (float)d * (1.0f / 1023.0f);   // linspace(0,1,1024)

    float a0 = 0.f, a1 = 0.f, a2 = 0.f, a3 = 0.f;
    #pragma unroll
    for (int j = 0; j < LCHUNK; j += 4) {          // fully unrolled, const addrs
        const float2 v0 = sxp[j + 0];              // wave-uniform: pure broadcast
        const float2 v1 = sxp[j + 1];
        const float2 v2 = sxp[j + 2];
        const float2 v3 = sxp[j + 3];
        a0 += __builtin_amdgcn_sinf(__builtin_amdgcn_fractf(fmaf(v0.x, t, v0.y)));
        a1 += __builtin_amdgcn_sinf(__builtin_amdgcn_fractf(fmaf(v1.x, t, v1.y)));
        a2 += __builtin_amdgcn_sinf(__builtin_amdgcn_fractf(fmaf(v2.x, t, v2.y)));
        a3 += __builtin_amdgcn_sinf(__builtin_amdgcn_fractf(fmaf(v3.x, t, v3.y)));
    }
    atomicAdd(&signal[d], (a0 + a1) + (a2 + a3));  // 512 adds/address, pipelined
}

// Stage 2: out[r] = b[r] + dot(signal, W[r, :])   (x @ W.T)
// One 64-lane wave per row; float4 loads, shuffle reduce. (R0-proven.)
__global__ __launch_bounds__(256) void matvec_kernel(const float* __restrict__ W,
                                                     const float* __restrict__ b,
                                                     const float* __restrict__ signal,
                                                     float* __restrict__ out) {
    const int wave = threadIdx.x >> 6;
    const int lane = threadIdx.x & 63;
    const int row  = blockIdx.x * 4 + wave;

    const float4* Wr = (const float4*)(W + (size_t)row * D_MODEL);
    const float4* S  = (const float4*)signal;

    float sum = 0.f;
    #pragma unroll
    for (int k = 0; k < 4; ++k) {
        const float4 w4 = Wr[lane + 64 * k];
        const float4 s4 = S[lane + 64 * k];
        sum += w4.x * s4.x + w4.y * s4.y + w4.z * s4.z + w4.w * s4.w;
    }
    #pragma unroll
    for (int off = 32; off > 0; off >>= 1)
        sum += __shfl_down(sum, off, 64);
    if (lane == 0) out[row] = sum + b[row];
}

extern "C" void kernel_launch(void* const* d_in, const int* in_sizes, int n_in,
                              void* d_out, int out_size, void* d_ws, size_t ws_size,
                              hipStream_t stream) {
    const float* x = (const float*)d_in[0];   // inputs [32768]
    const float* W = (const float*)d_in[1];   // W [1024,1024]
    const float* b = (const float*)d_in[2];   // b [1024]
    float* out    = (float*)d_out;            // [1024]
    float* signal = (float*)d_ws;             // 4 KB accumulator in workspace

    hipMemsetAsync(signal, 0, D_MODEL * sizeof(float), stream);
    signal_kernel<<<NBLK_S, 256, 0, stream>>>(x, signal);
    matvec_kernel<<<D_MODEL / 4, 256, 0, stream>>>(W, b, signal, out);
}

// Round 4
// 70.410 us; speedup vs baseline: 1.6089x; 1.0875x over previous
//
#include <hip/hip_runtime.h>

#define L_TOTAL 32768
#define D_MODEL 1024
#define LCHUNK  128                        // l's per signal block
#define NCH     (L_TOTAL / LCHUNK)         // 256 l-chunks
#define NQ      (D_MODEL / 256)            // 4 d-quarters (256 threads each)
#define NBLK_S  (NCH * NQ)                 // 1024 blocks -> 4/CU, 16 waves/CU

// Stage 1: part[c][d] = sum_{l in chunk c} sin(2*pi * x[l] * (t[d] + log1p(l)))
// NON-ATOMIC coalesced partial stores (atomic fan-in was the R3 suspect).
// Inner loop: wave-uniform LDS broadcast (1 address/iter), 4 accumulators.
__global__ __launch_bounds__(256) void signal_kernel(const float* __restrict__ x,
                                                     float* __restrict__ part) {
    __shared__ float2 sxp[LCHUNK];          // {x[l], x[l]*log1p(l)}  1 KB
    const int tid   = threadIdx.x;
    const int q     = blockIdx.x & (NQ - 1);
    const int c     = blockIdx.x >> 2;
    const int lbase = c * LCHUNK;

    if (tid < LCHUNK) {
        const int l   = lbase + tid;
        const float xv = x[l];
        sxp[tid] = make_float2(xv, xv * __logf(1.0f + (float)l));
    }
    __syncthreads();

    const int   d = q * 256 + tid;
    const float t = (float)d * (1.0f / 1023.0f);   // linspace(0,1,1024)

    float a0 = 0.f, a1 = 0.f, a2 = 0.f, a3 = 0.f;
    #pragma unroll
    for (int j = 0; j < LCHUNK; j += 4) {          // const addrs: pure broadcast
        const float2 v0 = sxp[j + 0];
        const float2 v1 = sxp[j + 1];
        const float2 v2 = sxp[j + 2];
        const float2 v3 = sxp[j + 3];
        a0 += __builtin_amdgcn_sinf(__builtin_amdgcn_fractf(fmaf(v0.x, t, v0.y)));
        a1 += __builtin_amdgcn_sinf(__builtin_amdgcn_fractf(fmaf(v1.x, t, v1.y)));
        a2 += __builtin_amdgcn_sinf(__builtin_amdgcn_fractf(fmaf(v2.x, t, v2.y)));
        a3 += __builtin_amdgcn_sinf(__builtin_amdgcn_fractf(fmaf(v3.x, t, v3.y)));
    }
    part[c * D_MODEL + d] = (a0 + a1) + (a2 + a3);  // coalesced 1KB/block, no RMW
}

// Stage 1b: signal[d] = sum_c part[c][d].  1 MB, L2-resident. 16 blocks x 256 thr.
__global__ __launch_bounds__(256) void reduce_kernel(const float* __restrict__ part,
                                                     float* __restrict__ signal) {
    __shared__ float red[4][64];
    const int tid = threadIdx.x;
    const int dd  = blockIdx.x * 64 + (tid & 63);   // d
    const int s   = tid >> 6;                       // c-slice 0..3 (64 c's each)
    float acc = 0.f;
    #pragma unroll 8
    for (int j = 0; j < NCH / 4; ++j)               // coalesced 256B per wave-iter
        acc += part[(s * (NCH / 4) + j) * D_MODEL + dd];
    red[s][tid & 63] = acc;
    __syncthreads();
    if (tid < 64)
        signal[blockIdx.x * 64 + tid] =
            (red[0][tid] + red[1][tid]) + (red[2][tid] + red[3][tid]);
}

// Stage 2: out[r] = b[r] + dot(signal, W[r, :]).  2 waves per row (8 waves/block)
// for latency hiding; float4 loads, shuffle reduce, LDS pair-combine.
__global__ __launch_bounds__(512) void matvec_kernel(const float* __restrict__ W,
                                                     const float* __restrict__ b,
                                                     const float* __restrict__ signal,
                                                     float* __restrict__ out) {
    __shared__ float rsum[8];
    const int tid  = threadIdx.x;
    const int wv   = tid >> 6;               // 0..7
    const int lane = tid & 63;
    const int row  = blockIdx.x * 4 + (wv >> 1);
    const int h    = wv & 1;                 // column half

    const float4* Wr = (const float4*)(W + (size_t)row * D_MODEL);
    const float4* S  = (const float4*)signal;

    float sum = 0.f;
    #pragma unroll
    for (int k = h * 2; k < h * 2 + 2; ++k) {
        const float4 w4 = Wr[lane + 64 * k];
        const float4 s4 = S[lane + 64 * k];
        sum += w4.x * s4.x + w4.y * s4.y + w4.z * s4.z + w4.w * s4.w;
    }
    #pragma unroll
    for (int off = 32; off > 0; off >>= 1)
        sum += __shfl_down(sum, off, 64);
    if (lane == 0) rsum[wv] = sum;
    __syncthreads();
    if (tid < 4) {
        const int r = blockIdx.x * 4 + tid;
        out[r] = rsum[2 * tid] + rsum[2 * tid + 1] + b[r];
    }
}

extern "C" void kernel_launch(void* const* d_in, const int* in_sizes, int n_in,
                              void* d_out, int out_size, void* d_ws, size_t ws_size,
                              hipStream_t stream) {
    const float* x = (const float*)d_in[0];   // inputs [32768]
    const float* W = (const float*)d_in[1];   // W [1024,1024]
    const float* b = (const float*)d_in[2];   // b [1024]
    float* out    = (float*)d_out;            // [1024]
    float* part   = (float*)d_ws;             // [256][1024] partials, 1 MB
    float* signal = part + NCH * D_MODEL;     // [1024] reduced signal

    // No memset: partials fully overwritten, signal fully written by reduce.
    signal_kernel<<<NBLK_S, 256, 0, stream>>>(x, part);
    reduce_kernel<<<D_MODEL / 64, 256, 0, stream>>>(part, signal);
    matvec_kernel<<<D_MODEL / 4, 512, 0, stream>>>(W, b, signal, out);
}